// Round 3
// baseline (374.240 us; speedup 1.0000x reference)
//
#include <hip/hip_runtime.h>
#include <cmath>

// ---- types -----------------------------------------------------------------
typedef float  f32x4  __attribute__((ext_vector_type(4)));
typedef __bf16 bf16x8 __attribute__((ext_vector_type(8)));
typedef __bf16 bf16x4 __attribute__((ext_vector_type(4)));

#define MFMA16(acc, a, b) (acc) = __builtin_amdgcn_mfma_f32_16x16x32_bf16((a), (b), (acc), 0, 0, 0)

// Geometry: x is [B=2, C=128, D=16, H=64, W=64] fp32.
// flat = b*8388608 + c*65536 + d*4096 + hw.
// qkv_w row map: head h rows [96h,96h+96): q +0, k +32, v +64.
// Attention-output channel numbering: ch = h*32 + d  (head-major).

// wave-scratch swizzles (XOR keeps 16B-aligned reads conflict-free, T2/G4):
// 256B-pitch [16 pos][128 ch bf16] (k2 scratch)
__device__ __forceinline__ int swz(int row, int colByte){ return row*256 + (colByte ^ ((row & 7) << 4)); }
// 64B-pitch [64 rows][32 pos bf16] (k1 transpose scratch)
__device__ __forceinline__ int swzT(int row, int posByte){ return row*64 + (posByte ^ (((row >> 2) & 3) << 4)); }

// 8 consecutive fp32 weights -> bf16x8 A-fragment (global, L2-hot).
__device__ __forceinline__ bf16x8 ldw(const float* __restrict__ p){
  f32x4 a = *((const f32x4*)p);
  f32x4 b = *((const f32x4*)(p + 4));
  bf16x8 r;
  #pragma unroll
  for (int i = 0; i < 4; ++i){ r[i] = (__bf16)a[i]; r[i+4] = (__bf16)b[i]; }
  return r;
}

// ---- K1: k/v projection + LayerNorm + block-partial kv ---------------------
// grid 1024, block 256 = 4 waves; wave w owns 32 positions (bx*128 + w*32),
// computes ALL heads for them. No inter-wave sharing except the final kv
// accumulation (LDS atomicAdd, f32). Barriers: 2 per block.
__global__ __launch_bounds__(256, 4) void k1_kv(
    const float* __restrict__ x, const float* __restrict__ qkv_w, const float* __restrict__ qkv_b,
    const float* __restrict__ klw, const float* __restrict__ klb,
    const float* __restrict__ vlw, const float* __restrict__ vlb,
    __bf16* __restrict__ part){
  __shared__ float kvS[4096];      // [h][d][c] f32 block accumulator
  __shared__ char  tS[4][4096];    // per-wave [64 rows][32 pos] bf16 (k' rows 0-31, v' rows 32-63)
  int t = threadIdx.x, lane = t & 63, w = t >> 6, l15 = lane & 15, l4 = lane >> 4;

  #pragma unroll
  for (int i = 0; i < 4; ++i) *((f32x4*)kvS + t * 4 + i) = f32x4{0.f, 0.f, 0.f, 0.f};
  __syncthreads();

  int bx = blockIdx.x, bd = bx >> 5, b = bd >> 4, d = bd & 15;
  const float* xw = x + b * 8388608 + d * 4096 + (bx & 31) * 128 + w * 32;

  // x B-fragments in registers: [n2-tile][kf]: k-elems = ch kf*32+l4*8.., col = pos n2*16+l15
  bf16x8 xf[2][4];
  #pragma unroll
  for (int n2 = 0; n2 < 2; ++n2)
    #pragma unroll
    for (int kf = 0; kf < 4; ++kf)
      #pragma unroll
      for (int j = 0; j < 8; ++j)
        xf[n2][kf][j] = (__bf16)xw[(kf * 32 + l4 * 8 + j) * 65536 + n2 * 16 + l15];

  char* ts = tS[w];
  #pragma unroll 1
  for (int h = 0; h < 4; ++h){
    // ---- project k (ph=0) then v (ph=1): 32 ch x 32 pos, LN, -> ts --------
    #pragma unroll 1
    for (int ph = 0; ph < 2; ++ph){
      int po = 96 * h + 32 + 32 * ph;
      f32x4 pa[2][2] = {};           // [m2][n2]: rows c=m2*16+l4*4+r, cols pos=n2*16+l15
      #pragma unroll
      for (int kf = 0; kf < 4; ++kf){
        bf16x8 a0 = ldw(qkv_w + (po + l15) * 128 + kf * 32 + l4 * 8);
        bf16x8 a1 = ldw(qkv_w + (po + 16 + l15) * 128 + kf * 32 + l4 * 8);
        MFMA16(pa[0][0], a0, xf[0][kf]); MFMA16(pa[0][1], a0, xf[1][kf]);
        MFMA16(pa[1][0], a1, xf[0][kf]); MFMA16(pa[1][1], a1, xf[1][kf]);
      }
      const float* lwp = (ph ? vlw : klw) + 32 * h;
      const float* lbp = (ph ? vlb : klb) + 32 * h;
      f32x4 b0  = *(const f32x4*)(qkv_b + po + l4 * 4);
      f32x4 b1  = *(const f32x4*)(qkv_b + po + 16 + l4 * 4);
      f32x4 lw0 = *(const f32x4*)(lwp + l4 * 4), lw1 = *(const f32x4*)(lwp + 16 + l4 * 4);
      f32x4 lb0 = *(const f32x4*)(lbp + l4 * 4), lb1 = *(const f32x4*)(lbp + 16 + l4 * 4);
      #pragma unroll
      for (int n2 = 0; n2 < 2; ++n2){
        f32x4 v0 = pa[0][n2] + b0;
        f32x4 v1 = pa[1][n2] + b1;
        // LayerNorm over the head's 32 channels (ddof=1, denom = std+eps):
        // per pos sum over m2,r in-reg then across l4 lanes (xor 16,32).
        float s1 = v0[0]+v0[1]+v0[2]+v0[3] + v1[0]+v1[1]+v1[2]+v1[3];
        float s2 = v0[0]*v0[0]+v0[1]*v0[1]+v0[2]*v0[2]+v0[3]*v0[3]
                 + v1[0]*v1[0]+v1[1]*v1[1]+v1[2]*v1[2]+v1[3]*v1[3];
        s1 += __shfl_xor(s1, 16); s2 += __shfl_xor(s2, 16);
        s1 += __shfl_xor(s1, 32); s2 += __shfl_xor(s2, 32);
        float m   = s1 * (1.f / 32.f);
        float var = fmaxf((s2 - 32.f * m * m) * (1.f / 31.f), 0.f);
        float inv = 1.f / (sqrtf(var) + 1e-5f);
        v0 = (v0 - m) * inv * lw0 + lb0;
        v1 = (v1 - m) * inv * lw1 + lb1;
        int pB = (n2 * 16 + l15) * 2;
        #pragma unroll
        for (int r = 0; r < 4; ++r){
          *(__bf16*)(ts + swzT(ph * 32 + l4 * 4 + r, pB))      = (__bf16)v0[r];
          *(__bf16*)(ts + swzT(ph * 32 + 16 + l4 * 4 + r, pB)) = (__bf16)v1[r];
        }
      }
    }
    // ---- outer product kv[c][d] += sum_pos k'[c,pos] v'[d,pos] (K=32) -----
    bf16x8 ka0 = *(const bf16x8*)(ts + swzT(l15,      l4 * 16));
    bf16x8 ka1 = *(const bf16x8*)(ts + swzT(16 + l15, l4 * 16));
    bf16x8 vb0 = *(const bf16x8*)(ts + swzT(32 + l15, l4 * 16));
    bf16x8 vb1 = *(const bf16x8*)(ts + swzT(48 + l15, l4 * 16));
    f32x4 kva[2][2] = {};            // rows c, cols d
    MFMA16(kva[0][0], ka0, vb0); MFMA16(kva[0][1], ka0, vb1);
    MFMA16(kva[1][0], ka1, vb0); MFMA16(kva[1][1], ka1, vb1);
    float* kh = kvS + h * 1024;      // layout [d][c]
    #pragma unroll
    for (int m2 = 0; m2 < 2; ++m2)
      #pragma unroll
      for (int n2 = 0; n2 < 2; ++n2)
        #pragma unroll
        for (int r = 0; r < 4; ++r)
          atomicAdd(kh + (n2 * 16 + l15) * 32 + m2 * 16 + l4 * 4 + r, kva[m2][n2][r]);
  }
  __syncthreads();

  // store block partial as bf16: part[bx][h][d][c]
  __bf16* pb = part + (size_t)bx * 4096;
  #pragma unroll
  for (int i = 0; i < 4; ++i){
    f32x4 vv = *((f32x4*)kvS + t * 4 + i);
    bf16x4 pk;
    #pragma unroll
    for (int r = 0; r < 4; ++r) pk[r] = (__bf16)vv[r];
    *(bf16x4*)(pb + t * 16 + i * 4) = pk;
  }
}

// ---- K1.5: reduce 32 bf16 partials -> kv^T bf16 [bd][h][d][c], /4096 -------
__global__ __launch_bounds__(256) void k15_reduce(const __bf16* __restrict__ part,
                                                  __bf16* __restrict__ kvt){
  typedef __bf16 bf16x2 __attribute__((ext_vector_type(2)));
  int bx = blockIdx.x, t = threadIdx.x;
  int bd = bx >> 3, seg = bx & 7;
  int e = seg * 512 + t * 2;
  float s0 = 0.f, s1 = 0.f;
  #pragma unroll
  for (int sub = 0; sub < 32; ++sub){
    bf16x2 p = *(const bf16x2*)(part + (size_t)(bd * 32 + sub) * 4096 + e);
    s0 += (float)p[0]; s1 += (float)p[1];
  }
  bf16x2 o; o[0] = (__bf16)(s0 * (1.f / 4096.f)); o[1] = (__bf16)(s1 * (1.f / 4096.f));
  *(bf16x2*)(kvt + bd * 4096 + e) = o;
}

// ---- K2: q -> attention(+x) -> o1+gelu -> o2 + bias + x --------------------
// grid 2048, block 256 = 4 waves; wave w owns 16 positions (bx*64 + w*16) and
// computes all 128 channels itself. Wave-private LDS scratch, ZERO barriers.
__global__ __launch_bounds__(256, 5) void k2_main(
    const float* __restrict__ x, const float* __restrict__ qkv_w, const float* __restrict__ qkv_b,
    const float* __restrict__ o1w, const float* __restrict__ o1b,
    const float* __restrict__ o2w, const float* __restrict__ o2b,
    const __bf16* __restrict__ kvt, float* __restrict__ out){
  __shared__ char sc[4][4096];       // per-wave [16 pos][128 ch] bf16: q -> ret' -> h
  int t = threadIdx.x, lane = t & 63, w = t >> 6, l15 = lane & 15, l4 = lane >> 4;
  int bx = blockIdx.x, bd = bx >> 6, b = bd >> 4, d = bd & 15;
  int gofs = b * 8388608 + d * 4096 + (bx & 63) * 64 + w * 16;
  const float* xg = x + gofs;
  float* og = out + gofs;
  char* s = sc[w];

  // x in registers: B-frags for q-GEMM + residual frags (bf16, matches r2 precision)
  bf16x8 xq[4];
  #pragma unroll
  for (int kf = 0; kf < 4; ++kf)
    #pragma unroll
    for (int j = 0; j < 8; ++j)
      xq[kf][j] = (__bf16)xg[(kf * 32 + l4 * 8 + j) * 65536 + l15];
  bf16x4 xr[8];
  #pragma unroll
  for (int m = 0; m < 8; ++m)
    #pragma unroll
    for (int r = 0; r < 4; ++r)
      xr[m][r] = (__bf16)xg[(m * 16 + l4 * 4 + r) * 65536 + l15];

  // ---- q projection: all 4 heads, head-major channel order -> scratch -----
  {
    f32x4 acc[8] = {};
    #pragma unroll
    for (int kf = 0; kf < 4; ++kf)
      #pragma unroll
      for (int m = 0; m < 8; ++m){
        bf16x8 a = ldw(qkv_w + (96 * (m >> 1) + (m & 1) * 16 + l15) * 128 + kf * 32 + l4 * 8);
        MFMA16(acc[m], a, xq[kf]);
      }
    #pragma unroll
    for (int m = 0; m < 8; ++m){
      f32x4 qb = *(const f32x4*)(qkv_b + 96 * (m >> 1) + (m & 1) * 16 + l4 * 4);
      bf16x4 pk;
      #pragma unroll
      for (int r = 0; r < 4; ++r) pk[r] = (__bf16)(acc[m][r] + qb[r]);
      *(bf16x4*)(s + swz(l15, (m * 16 + l4 * 4) * 2)) = pk;
    }
  }

  // ---- attention per head: ret[d][pos] = kv^T . q, += x, -> scratch -------
  {
    const __bf16* kvb = kvt + bd * 4096;
    #pragma unroll
    for (int h = 0; h < 4; ++h){
      bf16x8 ka0 = *(const bf16x8*)(kvb + h * 1024 + l15 * 32 + l4 * 8);
      bf16x8 ka1 = *(const bf16x8*)(kvb + h * 1024 + (16 + l15) * 32 + l4 * 8);
      bf16x8 bq  = *(const bf16x8*)(s + swz(l15, h * 64 + l4 * 16));
      f32x4 r0 = {}, r1 = {};
      MFMA16(r0, ka0, bq);
      MFMA16(r1, ka1, bq);
      bf16x4 p0, p1;
      #pragma unroll
      for (int r = 0; r < 4; ++r){
        p0[r] = (__bf16)(r0[r] + (float)xr[2 * h][r]);
        p1[r] = (__bf16)(r1[r] + (float)xr[2 * h + 1][r]);
      }
      *(bf16x4*)(s + swz(l15, (h * 32 + l4 * 4) * 2)) = p0;
      *(bf16x4*)(s + swz(l15, (h * 32 + 16 + l4 * 4) * 2)) = p1;
    }
  }

  // ---- o1 + exact gelu -> scratch -----------------------------------------
  {
    bf16x8 rb[4];
    #pragma unroll
    for (int kf = 0; kf < 4; ++kf)
      rb[kf] = *(const bf16x8*)(s + swz(l15, kf * 64 + l4 * 16));
    f32x4 acc[8] = {};
    #pragma unroll
    for (int kf = 0; kf < 4; ++kf)
      #pragma unroll
      for (int m = 0; m < 8; ++m){
        bf16x8 a = ldw(o1w + (m * 16 + l15) * 128 + kf * 32 + l4 * 8);
        MFMA16(acc[m], a, rb[kf]);
      }
    #pragma unroll
    for (int m = 0; m < 8; ++m){
      f32x4 bb = *(const f32x4*)(o1b + m * 16 + l4 * 4);
      bf16x4 pk;
      #pragma unroll
      for (int r = 0; r < 4; ++r){
        float v = acc[m][r] + bb[r];
        v = 0.5f * v * (1.f + erff(v * 0.70710678118654752f));
        pk[r] = (__bf16)v;
      }
      *(bf16x4*)(s + swz(l15, (m * 16 + l4 * 4) * 2)) = pk;
    }
  }

  // ---- o2 + bias + residual, store fp32 -----------------------------------
  {
    bf16x8 hb[4];
    #pragma unroll
    for (int kf = 0; kf < 4; ++kf)
      hb[kf] = *(const bf16x8*)(s + swz(l15, kf * 64 + l4 * 16));
    f32x4 acc[8] = {};
    #pragma unroll
    for (int kf = 0; kf < 4; ++kf)
      #pragma unroll
      for (int m = 0; m < 8; ++m){
        bf16x8 a = ldw(o2w + (m * 16 + l15) * 128 + kf * 32 + l4 * 8);
        MFMA16(acc[m], a, hb[kf]);
      }
    #pragma unroll
    for (int m = 0; m < 8; ++m){
      f32x4 bb = *(const f32x4*)(o2b + m * 16 + l4 * 4);
      #pragma unroll
      for (int r = 0; r < 4; ++r)
        og[(m * 16 + l4 * 4 + r) * 65536 + l15] = acc[m][r] + bb[r] + (float)xr[m][r];
    }
  }
}

// ---- launch ----------------------------------------------------------------
extern "C" void kernel_launch(void* const* d_in, const int* in_sizes, int n_in,
                              void* d_out, int out_size, void* d_ws, size_t ws_size,
                              hipStream_t stream){
  const float* x     = (const float*)d_in[0];
  const float* qkv_w = (const float*)d_in[1];
  const float* qkv_b = (const float*)d_in[2];
  const float* o1w   = (const float*)d_in[3];
  const float* o1b   = (const float*)d_in[4];
  const float* o2w   = (const float*)d_in[5];
  const float* o2b   = (const float*)d_in[6];
  const float* klw   = (const float*)d_in[7];
  const float* klb   = (const float*)d_in[8];
  const float* vlw   = (const float*)d_in[9];
  const float* vlb   = (const float*)d_in[10];

  __bf16* part = (__bf16*)d_ws;                                    // 1024*4096*2 = 8 MiB
  __bf16* kvt  = (__bf16*)((char*)d_ws + (size_t)1024 * 4096 * 2); // 32*4096*2 = 256 KiB

  k1_kv<<<1024, 256, 0, stream>>>(x, qkv_w, qkv_b, klw, klb, vlw, vlb, part);
  k15_reduce<<<256, 256, 0, stream>>>(part, kvt);
  k2_main<<<2048, 256, 0, stream>>>(x, qkv_w, qkv_b, o1w, o1b, o2w, o2b, kvt, (float*)d_out);
}

// Round 4
// 91.019 us; speedup vs baseline: 4.1117x; 4.1117x over previous
//
#include <hip/hip_runtime.h>
#include <cmath>

// ---- types -----------------------------------------------------------------
typedef float  f32x4  __attribute__((ext_vector_type(4)));
typedef __bf16 bf16x8 __attribute__((ext_vector_type(8)));
typedef __bf16 bf16x4 __attribute__((ext_vector_type(4)));
typedef __bf16 bf16x2 __attribute__((ext_vector_type(2)));

#define MFMA16(acc, a, b) (acc) = __builtin_amdgcn_mfma_f32_16x16x32_bf16((a), (b), (acc), 0, 0, 0)

// Geometry: x [B=2, C=128, D=16, H=64, W=64] fp32; flat = b*8388608 + c*65536 + d*4096 + hw.
// qkv_w rows: head h occupies [96h, 96h+96): q +0, k +32, v +64.
// Attention-output channel numbering: ch = 32h + d (head-major).

// LDS swizzles (XOR keeps 16B-aligned access conflict-light, T2/G4)
__device__ __forceinline__ int swz(int row, int colByte){ return row*256 + (colByte ^ ((row & 7) << 4)); }   // pitch 256B
__device__ __forceinline__ int swzP(int row, int colByte){ return row*128 + (colByte ^ ((row & 7) << 4)); }  // pitch 128B

// coalesced fp32 x-tile load: 64 pos x 128 ch; thread t: pos=t&63 (256B/instr), 32 floats
__device__ __forceinline__ void loadx(float* sx, const float* __restrict__ xb, int t){
  int p = t & 63, cg = t >> 6;
  const float* col = xb + p;
  #pragma unroll
  for (int i = 0; i < 4; ++i)
    #pragma unroll
    for (int j = 0; j < 8; ++j)
      sx[i*8 + j] = col[(cg*8 + i*32 + j) * 65536];
}
// cvt + LDS write of staged regs -> bf16 [pos][ch] swizzled tile
__device__ __forceinline__ void writex(const float* sx, char* ldsX, int t){
  int p = t & 63, cg = t >> 6;
  #pragma unroll
  for (int i = 0; i < 4; ++i){
    bf16x8 u;
    #pragma unroll
    for (int j = 0; j < 8; ++j) u[j] = (__bf16)sx[i*8 + j];
    *(bf16x8*)(ldsX + swz(p, cg*16 + i*64)) = u;
  }
}

// ---- W-prep: fp32 weights -> bf16 once (qkv_w | o1w | o2w concatenated) ----
__global__ __launch_bounds__(256) void wprep(const float* __restrict__ qkv_w,
                                             const float* __restrict__ o1w,
                                             const float* __restrict__ o2w,
                                             __bf16* __restrict__ w16){
  int e = (blockIdx.x * 256 + threadIdx.x) * 4;   // 80 blocks -> 81920 elems
  const float* src; int off;
  if (e < 49152)      { src = qkv_w; off = e; }
  else if (e < 65536) { src = o1w;   off = e - 49152; }
  else                { src = o2w;   off = e - 65536; }
  f32x4 v = *(const f32x4*)(src + off);
  bf16x4 o;
  #pragma unroll
  for (int r = 0; r < 4; ++r) o[r] = (__bf16)v[r];
  *(bf16x4*)(w16 + e) = o;
}

// ---- K1: k/v projection + LayerNorm + per-block kv partial -----------------
// grid 1024 = 32 bd-slices x 32 subs; block 256 = 4 waves; wave w = head w.
// 128 pos per block as 2 chunks of 64; chunk-1 x prefetched into regs.
// LDS: x tile 16K + 4x8K wave-private k'/v' scratch. 3 barriers total.
__global__ __launch_bounds__(256, 3) void k1_kv(
    const float* __restrict__ x, const __bf16* __restrict__ w16, const float* __restrict__ qkv_b,
    const float* __restrict__ klw, const float* __restrict__ klb,
    const float* __restrict__ vlw, const float* __restrict__ vlb,
    __bf16* __restrict__ part){
  __shared__ char ldsX[16384];
  __shared__ char tS[4][8192];
  int t = threadIdx.x, lane = t & 63, w = t >> 6, l15 = lane & 15, l4 = lane >> 4;
  int bx = blockIdx.x, bd = bx >> 5, b = bd >> 4, d = bd & 15;
  const float* xb = x + (size_t)b*8388608 + d*4096 + (bx & 31)*128;
  char* ks = tS[w];           // k' [32 ch][64 pos] bf16, pitch 128B
  char* vs = tS[w] + 4096;    // v'
  f32x4 kv[2][2] = {};        // [m: d-tiles][n: c-tiles], accumulates over chunks

  float sx[32];
  loadx(sx, xb, t);
  writex(sx, ldsX, t);
  __syncthreads();

  #pragma unroll
  for (int ch = 0; ch < 2; ++ch){
    if (ch == 0){
      loadx(sx, xb + 64, t);            // prefetch chunk 1 (lands during compute)
    } else {
      __syncthreads();                  // all waves done reading ldsX
      writex(sx, ldsX, t);
      __syncthreads();
    }
    // ---- project k (ph=0) then v (ph=1): 32 ch x 64 pos, +bias, LN --------
    #pragma unroll
    for (int ph = 0; ph < 2; ++ph){
      int po = 96*w + 32 + 32*ph;
      f32x4 acc[2][4] = {};
      #pragma unroll
      for (int kf = 0; kf < 4; ++kf){
        bf16x8 a0 = *(const bf16x8*)(w16 + (po + l15)*128 + kf*32 + l4*8);
        bf16x8 a1 = *(const bf16x8*)(w16 + (po + 16 + l15)*128 + kf*32 + l4*8);
        bf16x8 bn0 = *(const bf16x8*)(ldsX + swz(l15,      kf*64 + l4*16));
        bf16x8 bn1 = *(const bf16x8*)(ldsX + swz(16 + l15, kf*64 + l4*16));
        bf16x8 bn2 = *(const bf16x8*)(ldsX + swz(32 + l15, kf*64 + l4*16));
        bf16x8 bn3 = *(const bf16x8*)(ldsX + swz(48 + l15, kf*64 + l4*16));
        MFMA16(acc[0][0], a0, bn0); MFMA16(acc[0][1], a0, bn1);
        MFMA16(acc[0][2], a0, bn2); MFMA16(acc[0][3], a0, bn3);
        MFMA16(acc[1][0], a1, bn0); MFMA16(acc[1][1], a1, bn1);
        MFMA16(acc[1][2], a1, bn2); MFMA16(acc[1][3], a1, bn3);
      }
      const float* lwp = (ph ? vlw : klw) + 32*w;
      const float* lbp = (ph ? vlb : klb) + 32*w;
      f32x4 b0  = *(const f32x4*)(qkv_b + po + l4*4);
      f32x4 b1  = *(const f32x4*)(qkv_b + po + 16 + l4*4);
      f32x4 lw0 = *(const f32x4*)(lwp + l4*4), lw1 = *(const f32x4*)(lwp + 16 + l4*4);
      f32x4 lb0 = *(const f32x4*)(lbp + l4*4), lb1 = *(const f32x4*)(lbp + 16 + l4*4);
      char* dst = ph ? vs : ks;
      #pragma unroll
      for (int n = 0; n < 4; ++n){
        f32x4 v0 = acc[0][n] + b0;
        f32x4 v1 = acc[1][n] + b1;
        // LN over 32 ch per pos (ddof=1, denom = std+eps): in-lane 8 + xor 16,32
        float s1 = v0[0]+v0[1]+v0[2]+v0[3] + v1[0]+v1[1]+v1[2]+v1[3];
        float s2 = v0[0]*v0[0]+v0[1]*v0[1]+v0[2]*v0[2]+v0[3]*v0[3]
                 + v1[0]*v1[0]+v1[1]*v1[1]+v1[2]*v1[2]+v1[3]*v1[3];
        s1 += __shfl_xor(s1, 16); s2 += __shfl_xor(s2, 16);
        s1 += __shfl_xor(s1, 32); s2 += __shfl_xor(s2, 32);
        float m   = s1 * (1.f/32.f);
        float var = fmaxf((s2 - 32.f*m*m) * (1.f/31.f), 0.f);
        float inv = 1.f / (sqrtf(var) + 1e-5f);
        v0 = (v0 - m) * inv * lw0 + lb0;
        v1 = (v1 - m) * inv * lw1 + lb1;
        int pB = (16*n + l15) * 2;
        #pragma unroll
        for (int r = 0; r < 4; ++r){
          *(__bf16*)(dst + swzP(l4*4 + r, pB))      = (__bf16)v0[r];
          *(__bf16*)(dst + swzP(16 + l4*4 + r, pB)) = (__bf16)v1[r];
        }
      }
    }
    // ---- outer product: kv[d][c] += sum_pos v'[d,pos] k'[c,pos] (K=64) ----
    #pragma unroll
    for (int kf = 0; kf < 2; ++kf){
      bf16x8 av0 = *(const bf16x8*)(vs + swzP(l15,      kf*64 + l4*16));
      bf16x8 av1 = *(const bf16x8*)(vs + swzP(16 + l15, kf*64 + l4*16));
      bf16x8 bk0 = *(const bf16x8*)(ks + swzP(l15,      kf*64 + l4*16));
      bf16x8 bk1 = *(const bf16x8*)(ks + swzP(16 + l15, kf*64 + l4*16));
      MFMA16(kv[0][0], av0, bk0); MFMA16(kv[0][1], av0, bk1);
      MFMA16(kv[1][0], av1, bk0); MFMA16(kv[1][1], av1, bk1);
    }
  }

  // store partial: part[bx][h=w][d][c], c fast (matches kvt layout)
  __bf16* pb = part + (size_t)bx*4096 + w*1024;
  #pragma unroll
  for (int m = 0; m < 2; ++m)
    #pragma unroll
    for (int n = 0; n < 2; ++n)
      #pragma unroll
      for (int r = 0; r < 4; ++r)
        pb[(16*m + l4*4 + r)*32 + 16*n + l15] = (__bf16)kv[m][n][r];
}

// ---- K1.5: reduce 32 partials -> kvt bf16 [bd][h][d][c], /4096 -------------
__global__ __launch_bounds__(256) void k15_reduce(const __bf16* __restrict__ part,
                                                  __bf16* __restrict__ kvt){
  int bx = blockIdx.x, t = threadIdx.x;
  int bd = bx >> 3, seg = bx & 7;
  int e = seg * 512 + t * 2;
  float s0 = 0.f, s1 = 0.f;
  #pragma unroll
  for (int sub = 0; sub < 32; ++sub){
    bf16x2 p = *(const bf16x2*)(part + (size_t)(bd * 32 + sub) * 4096 + e);
    s0 += (float)p[0]; s1 += (float)p[1];
  }
  bf16x2 o; o[0] = (__bf16)(s0 * (1.f / 4096.f)); o[1] = (__bf16)(s1 * (1.f / 4096.f));
  *(bf16x2*)(kvt + bd * 4096 + e) = o;
}

// ---- K2: q -> attention(+x) -> o1+gelu -> o2 + bias + x --------------------
// grid 1024; block 256 = 4 waves; 2 tiles of 64 pos per block, x double-
// buffered with async-stage split. Wave w owns 32 output channels per GEMM.
__global__ __launch_bounds__(256, 3) void k2_main(
    const float* __restrict__ x, const __bf16* __restrict__ w16, const float* __restrict__ qkv_b,
    const float* __restrict__ o1b, const float* __restrict__ o2b,
    const __bf16* __restrict__ kvt, float* __restrict__ out){
  __shared__ char ldsX2[2][16384];   // x tiles (residual source, persists per tile)
  __shared__ char wk[16384];         // q -> ret -> h work buffer [64 pos][128 ch]
  int t = threadIdx.x, lane = t & 63, w = t >> 6, l15 = lane & 15, l4 = lane >> 4;
  int bx = blockIdx.x;
  const __bf16* w1 = w16 + 49152;
  const __bf16* w2 = w16 + 65536;
  int oo = 32 * w;

  float sx[32];
  {
    int tt = bx * 2, bd = tt >> 6;
    const float* xb0 = x + (size_t)(bd >> 4)*8388608 + (bd & 15)*4096 + (tt & 63)*64;
    loadx(sx, xb0, t);
    writex(sx, ldsX2[0], t);
  }
  __syncthreads();

  #pragma unroll
  for (int ti = 0; ti < 2; ++ti){
    int tt = bx * 2 + ti, bd = tt >> 6;
    size_t gofs = (size_t)(bd >> 4)*8388608 + (bd & 15)*4096 + (tt & 63)*64;
    float* ob = out + gofs;
    char* lx = ldsX2[ti];
    if (ti == 0){
      int t2 = tt + 1, bd2 = t2 >> 6;
      const float* xb1 = x + (size_t)(bd2 >> 4)*8388608 + (bd2 & 15)*4096 + (t2 & 63)*64;
      loadx(sx, xb1, t);               // prefetch tile 1 into regs (T14 issue-early)
    } else {
      __syncthreads();                 // S_A: tile-0 wk reads done; ldsX2[1] visible
    }

    // ---- Q: head w's 32 q-channels, all 64 pos; write wk own cols ---------
    {
      f32x4 acc[2][4] = {};
      #pragma unroll
      for (int kf = 0; kf < 4; ++kf){
        bf16x8 a0 = *(const bf16x8*)(w16 + (96*w + l15)*128 + kf*32 + l4*8);
        bf16x8 a1 = *(const bf16x8*)(w16 + (96*w + 16 + l15)*128 + kf*32 + l4*8);
        bf16x8 bn0 = *(const bf16x8*)(lx + swz(l15,      kf*64 + l4*16));
        bf16x8 bn1 = *(const bf16x8*)(lx + swz(16 + l15, kf*64 + l4*16));
        bf16x8 bn2 = *(const bf16x8*)(lx + swz(32 + l15, kf*64 + l4*16));
        bf16x8 bn3 = *(const bf16x8*)(lx + swz(48 + l15, kf*64 + l4*16));
        MFMA16(acc[0][0], a0, bn0); MFMA16(acc[0][1], a0, bn1);
        MFMA16(acc[0][2], a0, bn2); MFMA16(acc[0][3], a0, bn3);
        MFMA16(acc[1][0], a1, bn0); MFMA16(acc[1][1], a1, bn1);
        MFMA16(acc[1][2], a1, bn2); MFMA16(acc[1][3], a1, bn3);
      }
      #pragma unroll
      for (int m = 0; m < 2; ++m){
        f32x4 qb = *(const f32x4*)(qkv_b + 96*w + 16*m + l4*4);
        int cB = (oo + 16*m + l4*4) * 2;
        #pragma unroll
        for (int n = 0; n < 4; ++n){
          bf16x4 pk;
          #pragma unroll
          for (int r = 0; r < 4; ++r) pk[r] = (__bf16)(acc[m][n][r] + qb[r]);
          *(bf16x4*)(wk + swz(16*n + l15, cB)) = pk;
        }
      }
    }
    // ---- attn: ret[d][pos] = kvt . q, += x; wave-own cols (no barrier) ----
    {
      const __bf16* kvh = kvt + ((size_t)bd*4 + w)*1024;
      bf16x8 ka0 = *(const bf16x8*)(kvh + l15*32 + l4*8);
      bf16x8 ka1 = *(const bf16x8*)(kvh + (16 + l15)*32 + l4*8);
      f32x4 acc[2][4] = {};
      #pragma unroll
      for (int n = 0; n < 4; ++n){
        bf16x8 bq = *(const bf16x8*)(wk + swz(16*n + l15, oo*2 + l4*16));
        MFMA16(acc[0][n], ka0, bq);
        MFMA16(acc[1][n], ka1, bq);
      }
      #pragma unroll
      for (int m = 0; m < 2; ++m){
        int cB = (oo + 16*m + l4*4) * 2;
        #pragma unroll
        for (int n = 0; n < 4; ++n){
          bf16x4 xv = *(const bf16x4*)(lx + swz(16*n + l15, cB));
          bf16x4 pk;
          #pragma unroll
          for (int r = 0; r < 4; ++r) pk[r] = (__bf16)(acc[m][n][r] + (float)xv[r]);
          *(bf16x4*)(wk + swz(16*n + l15, cB)) = pk;
        }
      }
    }
    if (ti == 0) writex(sx, ldsX2[1], t);   // T14 write-late: loads landed during Q/attn
    __syncthreads();                        // S_B: ret complete (+ tile-1 x staged)

    // ---- O1: acc = o1w . ret ----------------------------------------------
    f32x4 acc1[2][4] = {};
    #pragma unroll
    for (int kf = 0; kf < 4; ++kf){
      bf16x8 a0 = *(const bf16x8*)(w1 + (oo + l15)*128 + kf*32 + l4*8);
      bf16x8 a1 = *(const bf16x8*)(w1 + (oo + 16 + l15)*128 + kf*32 + l4*8);
      bf16x8 bn0 = *(const bf16x8*)(wk + swz(l15,      kf*64 + l4*16));
      bf16x8 bn1 = *(const bf16x8*)(wk + swz(16 + l15, kf*64 + l4*16));
      bf16x8 bn2 = *(const bf16x8*)(wk + swz(32 + l15, kf*64 + l4*16));
      bf16x8 bn3 = *(const bf16x8*)(wk + swz(48 + l15, kf*64 + l4*16));
      MFMA16(acc1[0][0], a0, bn0); MFMA16(acc1[0][1], a0, bn1);
      MFMA16(acc1[0][2], a0, bn2); MFMA16(acc1[0][3], a0, bn3);
      MFMA16(acc1[1][0], a1, bn0); MFMA16(acc1[1][1], a1, bn1);
      MFMA16(acc1[1][2], a1, bn2); MFMA16(acc1[1][3], a1, bn3);
    }
    __syncthreads();                        // S_C: all ret reads done
    // tanh-GELU (max |err| ~3e-4 vs exact): g = v * sigmoid(v*(c1 + c2*v^2))
    #pragma unroll
    for (int m = 0; m < 2; ++m){
      f32x4 bb = *(const f32x4*)(o1b + oo + 16*m + l4*4);
      int cB = (oo + 16*m + l4*4) * 2;
      #pragma unroll
      for (int n = 0; n < 4; ++n){
        bf16x4 pk;
        #pragma unroll
        for (int r = 0; r < 4; ++r){
          float v = acc1[m][n][r] + bb[r];
          float z = v * (1.5957691216f + 0.0713548164f * v * v);
          float g = v / (1.f + __expf(-z));
          pk[r] = (__bf16)g;
        }
        *(bf16x4*)(wk + swz(16*n + l15, cB)) = pk;
      }
    }
    __syncthreads();                        // S_D: h complete

    // ---- O2 + bias + residual, store fp32 ---------------------------------
    f32x4 acc2[2][4] = {};
    #pragma unroll
    for (int kf = 0; kf < 4; ++kf){
      bf16x8 a0 = *(const bf16x8*)(w2 + (oo + l15)*128 + kf*32 + l4*8);
      bf16x8 a1 = *(const bf16x8*)(w2 + (oo + 16 + l15)*128 + kf*32 + l4*8);
      bf16x8 bn0 = *(const bf16x8*)(wk + swz(l15,      kf*64 + l4*16));
      bf16x8 bn1 = *(const bf16x8*)(wk + swz(16 + l15, kf*64 + l4*16));
      bf16x8 bn2 = *(const bf16x8*)(wk + swz(32 + l15, kf*64 + l4*16));
      bf16x8 bn3 = *(const bf16x8*)(wk + swz(48 + l15, kf*64 + l4*16));
      MFMA16(acc2[0][0], a0, bn0); MFMA16(acc2[0][1], a0, bn1);
      MFMA16(acc2[0][2], a0, bn2); MFMA16(acc2[0][3], a0, bn3);
      MFMA16(acc2[1][0], a1, bn0); MFMA16(acc2[1][1], a1, bn1);
      MFMA16(acc2[1][2], a1, bn2); MFMA16(acc2[1][3], a1, bn3);
    }
    #pragma unroll
    for (int m = 0; m < 2; ++m){
      int c0 = oo + 16*m + l4*4;
      f32x4 bb = *(const f32x4*)(o2b + c0);
      #pragma unroll
      for (int n = 0; n < 4; ++n){
        bf16x4 xv = *(const bf16x4*)(lx + swz(16*n + l15, c0*2));
        #pragma unroll
        for (int r = 0; r < 4; ++r)
          ob[(size_t)(c0 + r)*65536 + 16*n + l15] = acc2[m][n][r] + bb[r] + (float)xv[r];
      }
    }
  }
}

// ---- launch ----------------------------------------------------------------
extern "C" void kernel_launch(void* const* d_in, const int* in_sizes, int n_in,
                              void* d_out, int out_size, void* d_ws, size_t ws_size,
                              hipStream_t stream){
  const float* x     = (const float*)d_in[0];
  const float* qkv_w = (const float*)d_in[1];
  const float* qkv_b = (const float*)d_in[2];
  const float* o1w   = (const float*)d_in[3];
  const float* o1b   = (const float*)d_in[4];
  const float* o2w   = (const float*)d_in[5];
  const float* o2b   = (const float*)d_in[6];
  const float* klw   = (const float*)d_in[7];
  const float* klb   = (const float*)d_in[8];
  const float* vlw   = (const float*)d_in[9];
  const float* vlb   = (const float*)d_in[10];

  __bf16* part = (__bf16*)d_ws;                            // 1024*4096*2 = 8 MiB
  __bf16* kvt  = (__bf16*)((char*)d_ws + 8388608);         // 32*4096*2  = 256 KiB
  __bf16* w16  = (__bf16*)((char*)d_ws + 8650752);         // 81920*2    = 160 KiB

  wprep<<<80, 256, 0, stream>>>(qkv_w, o1w, o2w, w16);
  k1_kv<<<1024, 256, 0, stream>>>(x, w16, qkv_b, klw, klb, vlw, vlb, part);
  k15_reduce<<<256, 256, 0, stream>>>(part, kvt);
  k2_main<<<1024, 256, 0, stream>>>(x, w16, qkv_b, o1b, o2b, kvt, (float*)d_out);
}